// Round 14
// baseline (306.581 us; speedup 1.0000x reference)
//
#include <hip/hip_runtime.h>
#include <hip/hip_fp16.h>
#include <cstdint>

constexpr int BSHIFT = 9;               // 512 nodes per bucket
constexpr int NBUCK  = 256;             // max buckets (covers 131072 nodes)
constexpr int BUCKET_CAP = 6144;        // slot capacity; E/bucket ~ Poisson(5102), 14 sigma

struct alignas(16) H8 { __half2 a, b, c, d; };
struct alignas(8)  H4 { __half2 a, b; };

__device__ __forceinline__ float4 add4(float4 a, float4 b) {
    return make_float4(a.x + b.x, a.y + b.y, a.z + b.z, a.w + b.w);
}
__device__ __forceinline__ float4 mul4s(float4 a, float s) {
    return make_float4(a.x * s, a.y * s, a.z * s, a.w * s);
}
__device__ __forceinline__ void acc_h8(float4& A0, float4& A1, const H8 v, float s) {
    float2 f0 = __half22float2(v.a), f1 = __half22float2(v.b);
    float2 f2 = __half22float2(v.c), f3 = __half22float2(v.d);
    A0.x = fmaf(f0.x, s, A0.x); A0.y = fmaf(f0.y, s, A0.y);
    A0.z = fmaf(f1.x, s, A0.z); A0.w = fmaf(f1.y, s, A0.w);
    A1.x = fmaf(f2.x, s, A1.x); A1.y = fmaf(f2.y, s, A1.y);
    A1.z = fmaf(f3.x, s, A1.z); A1.w = fmaf(f3.y, s, A1.w);
}

// ---------------- CSR build ----------------

constexpr int EPT = 16;  // edges per thread; chunk = 4096
__global__ __launch_bounds__(256) void partition_edges(
    const int* __restrict__ src, const int* __restrict__ dst,
    int* __restrict__ bucketCur, int* __restrict__ pairs, int ne) {
    __shared__ int lcnt[NBUCK];
    __shared__ int lbase[NBUCK];
    int base = blockIdx.x * (256 * EPT);
    if (threadIdx.x < NBUCK) lcnt[threadIdx.x] = 0;
    __syncthreads();
    int2 ed[EPT];
    int  rnk[EPT];
#pragma unroll
    for (int j = 0; j < EPT; ++j) {
        int e = base + j * 256 + threadIdx.x;
        if (e < ne) {
            int d = dst[e];
            ed[j] = make_int2(src[e], d);
            rnk[j] = atomicAdd(&lcnt[d >> BSHIFT], 1);
        } else {
            ed[j].y = -1;
        }
    }
    __syncthreads();
    if (threadIdx.x < NBUCK) {
        int c = lcnt[threadIdx.x];
        lbase[threadIdx.x] = c ? atomicAdd(&bucketCur[threadIdx.x], c) : 0;
    }
    __syncthreads();
#pragma unroll
    for (int j = 0; j < EPT; ++j) {
        if (ed[j].y >= 0) {
            int b = ed[j].y >> BSHIFT;
            int p = lbase[b] + rnk[j];
            if (p < BUCKET_CAP)
                pairs[(size_t)b * BUCKET_CAP + p] =
                    (ed[j].x << BSHIFT) | (ed[j].y & ((1 << BSHIFT) - 1));
        }
    }
}

// One block per bucket: LDS histogram + inline bucket-base scan (absorbs the old
// scan_buckets dispatch) -> offs / dinv / global per-node cursors.
__global__ __launch_bounds__(256) void bucket_hist(
    const int* __restrict__ pairs, const int* __restrict__ bucketCnt,
    int* __restrict__ offs, int* __restrict__ cursor,
    float* __restrict__ dinv, int n, int ne, int nbuckets) {
    constexpr int BN = 1 << BSHIFT;  // 512
    __shared__ int sb[256];
    __shared__ int hist[BN];
    __shared__ int tmp[256];
    int b = blockIdx.x;
    int cnt = bucketCnt[b];
    const int* pb = pairs + (size_t)b * BUCKET_CAP;
    int nodeLo = b << BSHIFT;

    // bucket-base scan (every block recomputes; 256 ints, trivial)
    sb[threadIdx.x] = bucketCnt[threadIdx.x];
    hist[threadIdx.x] = 0;
    hist[threadIdx.x + 256] = 0;
    __syncthreads();
    for (int off = 1; off < 256; off <<= 1) {
        int t = (threadIdx.x >= (unsigned)off) ? sb[threadIdx.x - off] : 0;
        __syncthreads();
        sb[threadIdx.x] += t;
        __syncthreads();
    }
    int base = (b == 0) ? 0 : sb[b - 1];

    for (int e = threadIdx.x; e < cnt; e += 256)
        atomicAdd(&hist[pb[e] & (BN - 1)], 1);
    __syncthreads();

    int l0 = 2 * threadIdx.x, l1 = l0 + 1;
    int h0 = hist[l0], h1 = hist[l1];
    tmp[threadIdx.x] = h0 + h1;
    __syncthreads();
    for (int off = 1; off < 256; off <<= 1) {
        int t = (threadIdx.x >= (unsigned)off) ? tmp[threadIdx.x - off] : 0;
        __syncthreads();
        tmp[threadIdx.x] += t;
        __syncthreads();
    }
    int e0 = tmp[threadIdx.x] - (h0 + h1);
    int e1 = e0 + h0;
    int g0 = nodeLo + l0, g1 = nodeLo + l1;
    if (g0 < n) {
        offs[g0] = base + e0; cursor[g0] = base + e0;
        dinv[g0] = rsqrtf((float)(h0 + 1));
    }
    if (g1 < n) {
        offs[g1] = base + e1; cursor[g1] = base + e1;
        dinv[g1] = rsqrtf((float)(h1 + 1));
    }
    if (b == 0 && threadIdx.x == 0) offs[n] = ne;
}

// 4 blocks per bucket: scatter src into csr windows via L2-local global cursors.
__global__ __launch_bounds__(256) void bucket_fill(
    const int* __restrict__ pairs, const int* __restrict__ bucketCnt,
    int* __restrict__ cursor, int* __restrict__ csr) {
    int b = blockIdx.x >> 2;
    int q = blockIdx.x & 3;
    int cnt = bucketCnt[b];
    int nodeLo = b << BSHIFT;
    const int* pb = pairs + (size_t)b * BUCKET_CAP;
    int s = (cnt * q) >> 2, t = (cnt * (q + 1)) >> 2;
    for (int e = s + threadIdx.x; e < t; e += 256) {
        int p = pb[e];
        int node = nodeLo + (p & ((1 << BSHIFT) - 1));
        int pos = atomicAdd(&cursor[node], 1);
        csr[pos] = ((unsigned)p) >> BSHIFT;
    }
}

// ---------------- fp32 -> fp16 streaming convert ----------------
__global__ void cvt_f32_f16(const float* __restrict__ x, __half* __restrict__ o, int n4) {
    int i = blockIdx.x * blockDim.x + threadIdx.x;
    if (i < n4) {
        float4 v = ((const float4*)x)[i];
        H4 h;
        h.a = __floats2half2_rn(v.x, v.y);
        h.b = __floats2half2_rn(v.z, v.w);
        ((H4*)o)[i] = h;
    }
}

// ---------------- agg1: fp16 gather (K=64), fp32 accumulate, fp16 out ----------------
__global__ __launch_bounds__(256) void agg1_h(
    const __half* __restrict__ s, const int* __restrict__ offs,
    const int* __restrict__ csr, const float* __restrict__ dinv,
    __half* __restrict__ out, int n) {
    int lane = threadIdx.x & 7;
    int node = blockIdx.x * 32 + (threadIdx.x >> 3);
    if (node >= n) return;
    int f0 = lane * 8;
    float dv = dinv[node];

    float4 z = make_float4(0.f, 0.f, 0.f, 0.f);
    float4 a00 = z, a01 = z, a10 = z, a11 = z, a20 = z, a21 = z, a30 = z, a31 = z;
    {
        H8 sv = *(const H8*)&s[(size_t)node * 64 + f0];
        acc_h8(a00, a01, sv, dv);
    }
    int e0 = offs[node], e1 = offs[node + 1];
    int e = e0;
    for (; e + 4 <= e1; e += 4) {
        int i0 = csr[e], i1 = csr[e + 1], i2 = csr[e + 2], i3 = csr[e + 3];
        H8 v0 = *(const H8*)&s[(size_t)i0 * 64 + f0];
        H8 v1 = *(const H8*)&s[(size_t)i1 * 64 + f0];
        H8 v2 = *(const H8*)&s[(size_t)i2 * 64 + f0];
        H8 v3 = *(const H8*)&s[(size_t)i3 * 64 + f0];
        acc_h8(a00, a01, v0, dinv[i0]);
        acc_h8(a10, a11, v1, dinv[i1]);
        acc_h8(a20, a21, v2, dinv[i2]);
        acc_h8(a30, a31, v3, dinv[i3]);
    }
    for (; e < e1; ++e) {
        int sid = csr[e];
        H8 v = *(const H8*)&s[(size_t)sid * 64 + f0];
        acc_h8(a00, a01, v, dinv[sid]);
    }
    float4 A0 = add4(add4(a00, a10), add4(a20, a30));
    float4 A1 = add4(add4(a01, a11), add4(a21, a31));
    A0 = mul4s(A0, dv);
    A1 = mul4s(A1, dv);

    H8 h;
    h.a = __floats2half2_rn(A0.x, A0.y);
    h.b = __floats2half2_rn(A0.z, A0.w);
    h.c = __floats2half2_rn(A1.x, A1.y);
    h.d = __floats2half2_rn(A1.z, A1.w);
    *(H8*)&out[(size_t)node * 64 + f0] = h;
}

// ---------------- agg2: fp16 gather (M=50 in s64h rows), fp16 out (zero-padded) ---------
__global__ __launch_bounds__(256) void agg2_h16(
    const __half* __restrict__ s, const int* __restrict__ offs,
    const int* __restrict__ csr, const float* __restrict__ dinv,
    const float* __restrict__ b, __half* __restrict__ out, int n) {
    constexpr int MH = 50, SH = 64;
    int lane = threadIdx.x & 7;
    int node = blockIdx.x * 32 + (threadIdx.x >> 3);
    if (node >= n) return;
    int f0 = lane * 8;
    H8 zh{};
    if (f0 >= 56) {              // lane 7: pure zero-pad (halves 56..63)
        *(H8*)&out[(size_t)node * SH + f0] = zh;
        return;
    }
    float dv = dinv[node];

    float4 z = make_float4(0.f, 0.f, 0.f, 0.f);
    float4 a00 = z, a01 = z, a10 = z, a11 = z, a20 = z, a21 = z, a30 = z, a31 = z;
    {
        H8 sv = *(const H8*)&s[(size_t)node * SH + f0];
        acc_h8(a00, a01, sv, 1.0f);
    }
    int e0 = offs[node], e1 = offs[node + 1];
    int e = e0;
    for (; e + 4 <= e1; e += 4) {
        int i0 = csr[e], i1 = csr[e + 1], i2 = csr[e + 2], i3 = csr[e + 3];
        H8 v0 = *(const H8*)&s[(size_t)i0 * SH + f0];
        H8 v1 = *(const H8*)&s[(size_t)i1 * SH + f0];
        H8 v2 = *(const H8*)&s[(size_t)i2 * SH + f0];
        H8 v3 = *(const H8*)&s[(size_t)i3 * SH + f0];
        acc_h8(a00, a01, v0, 1.0f);
        acc_h8(a10, a11, v1, 1.0f);
        acc_h8(a20, a21, v2, 1.0f);
        acc_h8(a30, a31, v3, 1.0f);
    }
    for (; e < e1; ++e) {
        H8 v = *(const H8*)&s[(size_t)csr[e] * SH + f0];
        acc_h8(a00, a01, v, 1.0f);
    }
    float4 A0 = add4(add4(a00, a10), add4(a20, a30));
    float4 A1 = add4(add4(a01, a11), add4(a21, a31));
    float v[8] = {A0.x, A0.y, A0.z, A0.w, A1.x, A1.y, A1.z, A1.w};
#pragma unroll
    for (int i = 0; i < 8; ++i)
        v[i] = (f0 + i < MH) ? fmaxf(dv * v[i] + b[f0 + i], 0.0f) : 0.0f;
    H8 h;
    h.a = __floats2half2_rn(v[0], v[1]);
    h.b = __floats2half2_rn(v[2], v[3]);
    h.c = __floats2half2_rn(v[4], v[5]);
    h.d = __floats2half2_rn(v[6], v[7]);
    *(H8*)&out[(size_t)node * SH + f0] = h;
}

// ---------------- register-tiled GEMM: fp16 in/out, W in LDS ----------------
// KR = real K rows in W (rows >= KR staged as zero; Xs rows >= KR may be junk*0).
template <int K, int M, int NT, int XS, int OS, bool SCALE, bool BIAS_RELU, int KR>
__global__ __launch_bounds__(256) void gemm_tiled_h(
    const __half* __restrict__ x, const float* __restrict__ W,
    const float* __restrict__ dinv, const float* __restrict__ b,
    __half* __restrict__ out, int n) {
    static_assert(NT % 4 == 0 && K % 4 == 0 && OS % 4 == 0, "");
    constexpr int Mp  = (M + 3) & ~3;
    constexpr int MQ  = Mp / 4;
    constexpr int NTp = NT + 4;
    constexpr int NTILES = (NT / 4) * MQ;
    static_assert(NTILES <= 256, "");
    static_assert(M % 4 != 0 || KR == K, "float4 W path assumes KR==K");

    __shared__ float Xs[K * NTp];
    __shared__ float Ws[K * Mp];

    if constexpr (M % 4 == 0) {
        for (int i = threadIdx.x; i < K * M / 4; i += 256)
            ((float4*)Ws)[i] = ((const float4*)W)[i];
    } else if constexpr (M % 2 == 0) {
        constexpr int C2 = Mp / 2;
        for (int i = threadIdx.x; i < K * C2; i += 256) {
            int r = i / C2, c = i - r * C2;
            float2 v = make_float2(0.0f, 0.0f);
            if (r < KR) {
                if (c * 2 + 1 < M)  v = *(const float2*)&W[r * M + c * 2];
                else if (c * 2 < M) v = make_float2(W[r * M + c * 2], 0.0f);
            }
            *(float2*)&Ws[r * Mp + c * 2] = v;
        }
    } else {
        for (int i = threadIdx.x; i < K * Mp; i += 256) {
            int r = i / Mp, c = i - r * Mp;
            Ws[i] = (c < M && r < KR) ? W[r * M + c] : 0.0f;
        }
    }

    int nodeBase = blockIdx.x * NT;
    constexpr int KVH = (K % 8 == 0) ? 8 : 4;
    for (int it = threadIdx.x; it < NT * (K / KVH); it += 256) {
        int node = it % NT;
        int kv = it / NT;
        int gn = nodeBase + node;
        if constexpr (KVH == 8) {
            H8 h{};
            if (gn < n) h = *(const H8*)&x[(size_t)gn * XS + kv * 8];
            float2 f0_ = __half22float2(h.a), f1_ = __half22float2(h.b);
            float2 f2_ = __half22float2(h.c), f3_ = __half22float2(h.d);
            Xs[(kv * 8 + 0) * NTp + node] = f0_.x;
            Xs[(kv * 8 + 1) * NTp + node] = f0_.y;
            Xs[(kv * 8 + 2) * NTp + node] = f1_.x;
            Xs[(kv * 8 + 3) * NTp + node] = f1_.y;
            Xs[(kv * 8 + 4) * NTp + node] = f2_.x;
            Xs[(kv * 8 + 5) * NTp + node] = f2_.y;
            Xs[(kv * 8 + 6) * NTp + node] = f3_.x;
            Xs[(kv * 8 + 7) * NTp + node] = f3_.y;
        } else {
            H4 h{};
            if (gn < n) h = *(const H4*)&x[(size_t)gn * XS + kv * 4];
            float2 f0_ = __half22float2(h.a), f1_ = __half22float2(h.b);
            Xs[(kv * 4 + 0) * NTp + node] = f0_.x;
            Xs[(kv * 4 + 1) * NTp + node] = f0_.y;
            Xs[(kv * 4 + 2) * NTp + node] = f1_.x;
            Xs[(kv * 4 + 3) * NTp + node] = f1_.y;
        }
    }
    __syncthreads();

    int t = threadIdx.x;
    if (t >= NTILES) return;
    int ng = t / MQ, mq = t - ng * MQ;
    int n0 = ng * 4;
    int m0 = mq * 4;

    float acc[4][4];
#pragma unroll
    for (int j = 0; j < 4; ++j)
#pragma unroll
        for (int i = 0; i < 4; ++i) acc[j][i] = 0.0f;

#pragma unroll 4
    for (int k = 0; k < K; ++k) {
        float4 xv = *(const float4*)&Xs[k * NTp + n0];
        float4 wv = *(const float4*)&Ws[k * Mp + m0];
        acc[0][0] = fmaf(xv.x, wv.x, acc[0][0]); acc[0][1] = fmaf(xv.x, wv.y, acc[0][1]);
        acc[0][2] = fmaf(xv.x, wv.z, acc[0][2]); acc[0][3] = fmaf(xv.x, wv.w, acc[0][3]);
        acc[1][0] = fmaf(xv.y, wv.x, acc[1][0]); acc[1][1] = fmaf(xv.y, wv.y, acc[1][1]);
        acc[1][2] = fmaf(xv.y, wv.z, acc[1][2]); acc[1][3] = fmaf(xv.y, wv.w, acc[1][3]);
        acc[2][0] = fmaf(xv.z, wv.x, acc[2][0]); acc[2][1] = fmaf(xv.z, wv.y, acc[2][1]);
        acc[2][2] = fmaf(xv.z, wv.z, acc[2][2]); acc[2][3] = fmaf(xv.z, wv.w, acc[2][3]);
        acc[3][0] = fmaf(xv.w, wv.x, acc[3][0]); acc[3][1] = fmaf(xv.w, wv.y, acc[3][1]);
        acc[3][2] = fmaf(xv.w, wv.z, acc[3][2]); acc[3][3] = fmaf(xv.w, wv.w, acc[3][3]);
    }

#pragma unroll
    for (int j = 0; j < 4; ++j) {
        int nd = nodeBase + n0 + j;
        if (nd >= n) continue;
        float dv = SCALE ? dinv[nd] : 1.0f;
        float r[4];
#pragma unroll
        for (int i = 0; i < 4; ++i) {
            r[i] = acc[j][i];
            if (SCALE) r[i] *= dv;
            if (BIAS_RELU) r[i] = fmaxf(r[i] + b[m0 + i], 0.0f);
        }
        if (m0 + 3 < M) {
            H4 h;
            h.a = __floats2half2_rn(r[0], r[1]);
            h.b = __floats2half2_rn(r[2], r[3]);
            *(H4*)&out[(size_t)nd * OS + m0] = h;
        } else {
#pragma unroll
            for (int i = 0; i < 4; ++i)
                if (m0 + i < M) out[(size_t)nd * OS + m0 + i] = __float2half_rn(r[i]);
        }
    }
}

// ---------------- agg3 (fp16 gather, 1 line/row) + MLP head ----------------
__global__ __launch_bounds__(256) void agg3_mlp_h(
    const __half* __restrict__ s, const int* __restrict__ offs,
    const int* __restrict__ csr, const float* __restrict__ dinv,
    const float* __restrict__ bg,
    const float* __restrict__ Wl1, const float* __restrict__ bl1,
    const float* __restrict__ Wl2, const float* __restrict__ bl2,
    const float* __restrict__ Wl3, const float* __restrict__ bl3,
    float* __restrict__ out, int n) {
    constexpr int MH = 25, SH = 32, LPN = 4;
    __shared__ float W1s[625], W2s[250], W3s[10], b1s[25], b2s[10];
    __shared__ float accs[64 * 26];
    __shared__ float b3s;

    for (int i = threadIdx.x; i < 625; i += 256) W1s[i] = Wl1[i];
    for (int i = threadIdx.x; i < 250; i += 256) W2s[i] = Wl2[i];
    if (threadIdx.x < 10) { W3s[threadIdx.x] = Wl3[threadIdx.x]; b2s[threadIdx.x] = bl2[threadIdx.x]; }
    if (threadIdx.x < 25) b1s[threadIdx.x] = bl1[threadIdx.x];
    if (threadIdx.x == 0) b3s = bl3[0];

    int lane = threadIdx.x % LPN;
    int nl   = threadIdx.x / LPN;
    int node = blockIdx.x * 64 + nl;
    int f0 = lane * 8;

    if (node < n && f0 < MH) {
        float dv = dinv[node];
        float4 z = make_float4(0.f, 0.f, 0.f, 0.f);
        float4 a00 = z, a01 = z, a10 = z, a11 = z, a20 = z, a21 = z, a30 = z, a31 = z;
        {
            H8 sv = *(const H8*)&s[(size_t)node * SH + f0];
            acc_h8(a00, a01, sv, 1.0f);
        }
        int e0 = offs[node], e1 = offs[node + 1];
        int e = e0;
        for (; e + 4 <= e1; e += 4) {
            int i0 = csr[e], i1 = csr[e + 1], i2 = csr[e + 2], i3 = csr[e + 3];
            H8 v0 = *(const H8*)&s[(size_t)i0 * SH + f0];
            H8 v1 = *(const H8*)&s[(size_t)i1 * SH + f0];
            H8 v2 = *(const H8*)&s[(size_t)i2 * SH + f0];
            H8 v3 = *(const H8*)&s[(size_t)i3 * SH + f0];
            acc_h8(a00, a01, v0, 1.0f);
            acc_h8(a10, a11, v1, 1.0f);
            acc_h8(a20, a21, v2, 1.0f);
            acc_h8(a30, a31, v3, 1.0f);
        }
        for (; e < e1; ++e) {
            H8 v = *(const H8*)&s[(size_t)csr[e] * SH + f0];
            acc_h8(a00, a01, v, 1.0f);
        }
        float4 A0 = add4(add4(a00, a10), add4(a20, a30));
        float4 A1 = add4(add4(a01, a11), add4(a21, a31));
        float v[8] = {A0.x, A0.y, A0.z, A0.w, A1.x, A1.y, A1.z, A1.w};
#pragma unroll
        for (int i = 0; i < 8; ++i)
            if (f0 + i < MH)
                accs[nl * 26 + f0 + i] = fmaxf(dv * v[i] + bg[f0 + i], 0.0f);
    }
    __syncthreads();

    if (threadIdx.x < 64) {
        int nd = blockIdx.x * 64 + threadIdx.x;
        if (nd < n) {
            const float* xr = &accs[threadIdx.x * 26];
            float h1[25];
#pragma unroll
            for (int m = 0; m < 25; ++m) {
                float a = b1s[m];
#pragma unroll
                for (int k = 0; k < 25; ++k) a = fmaf(xr[k], W1s[k * 25 + m], a);
                h1[m] = fmaxf(a, 0.0f);
            }
            float h2[10];
#pragma unroll
            for (int m = 0; m < 10; ++m) {
                float a = b2s[m];
#pragma unroll
                for (int k = 0; k < 25; ++k) a = fmaf(h1[k], W2s[k * 10 + m], a);
                h2[m] = fmaxf(a, 0.0f);
            }
            float a = b3s;
#pragma unroll
            for (int k = 0; k < 10; ++k) a = fmaf(h2[k], W3s[k], a);
            out[nd] = fmaxf(a, 0.0f);
        }
    }
}

// ---------------- launch ----------------

extern "C" void kernel_launch(void* const* d_in, const int* in_sizes, int n_in,
                              void* d_out, int out_size, void* d_ws, size_t ws_size,
                              hipStream_t stream) {
    const float* x0  = (const float*)d_in[0];
    const float* W1  = (const float*)d_in[1];
    const float* b1  = (const float*)d_in[2];
    const float* W2  = (const float*)d_in[3];
    const float* b2  = (const float*)d_in[4];
    const float* W3  = (const float*)d_in[5];
    const float* b3  = (const float*)d_in[6];
    const float* Wl1 = (const float*)d_in[7];
    const float* bl1 = (const float*)d_in[8];
    const float* Wl2 = (const float*)d_in[9];
    const float* bl2 = (const float*)d_in[10];
    const float* Wl3 = (const float*)d_in[11];
    const float* bl3 = (const float*)d_in[12];
    const int*   edge = (const int*)d_in[13];

    int n  = in_sizes[0] / 64;      // 100000
    int ne = in_sizes[13] / 2;      // 1000000
    const int* esrc = edge;
    const int* edst = edge + ne;

    char* ws = (char*)d_ws;
    auto alloc = [&](size_t bytes) {
        char* p = ws;
        ws += (bytes + 255) & ~(size_t)255;
        return p;
    };
    int*    offs       = (int*)alloc((size_t)(n + 1) * 4);
    int*    bucketCur  = (int*)alloc(NBUCK * 4);
    int*    cursor     = (int*)alloc((size_t)n * 4);
    int*    csr        = (int*)alloc((size_t)ne * 4);
    float*  dinv       = (float*)alloc((size_t)n * 4);
    __half* x0h        = (__half*)alloc((size_t)n * 64 * 2);   // fp16 s64h (cvt out)
    __half* bufAh      = (__half*)alloc((size_t)n * 64 * 2);   // fp16 s64h (agg1 out)
    __half* bufBh      = (__half*)alloc((size_t)n * 112 * 2);  // fp16 s112h (gemm1 out)
    __half* bufDh      = (__half*)alloc((size_t)n * 64 * 2);   // fp16 s64h (gemm2 out)
    // aliases (ordered lifetimes):
    //   pairs (6.3MB) in bufBh: consumed by bucket_fill before gemm1 writes bufBh
    //   bufEh (agg2 out, s64h) aliases x0h (dead after agg1)
    //   bufCh (gemm3 out, s32h) aliases bufAh (dead after gemm1)
    int*    pairs = (int*)bufBh;
    __half* bufEh = x0h;
    __half* bufCh = bufAh;
    (void)ws_size; (void)n_in; (void)out_size;

    int nbuckets = (n + (1 << BSHIFT) - 1) >> BSHIFT;   // 196

    // CSR + dinv (memset + 3 dispatches)
    hipMemsetAsync(bucketCur, 0, NBUCK * 4, stream);
    partition_edges<<<(ne + 256 * EPT - 1) / (256 * EPT), 256, 0, stream>>>(
        esrc, edst, bucketCur, pairs, ne);
    bucket_hist<<<nbuckets, 256, 0, stream>>>(
        pairs, bucketCur, offs, cursor, dinv, n, ne, nbuckets);
    bucket_fill<<<4 * nbuckets, 256, 0, stream>>>(pairs, bucketCur, cursor, csr);

    // x0h = fp16(x0)
    cvt_f32_f16<<<(n * 16 + 255) / 256, 256, 0, stream>>>(x0, x0h, n * 16);

    // agg1: bufAh = fp16(ÂX)
    agg1_h<<<(n + 31) / 32, 256, 0, stream>>>(x0h, offs, csr, dinv, bufAh, n);

    // gemm1: bufBh = fp16(relu(bufAh@W1 + b1))   [K=64 -> M=100]
    gemm_tiled_h<64, 100, 40, 64, 112, false, true, 64><<<(n + 39) / 40, 256, 0, stream>>>(
        bufAh, W1, nullptr, b1, bufBh, n);

    // gemm2: bufDh = fp16((bufBh@W2)*dinv)       [K=100 -> M=50]
    gemm_tiled_h<100, 50, 64, 112, 64, true, false, 100><<<(n + 63) / 64, 256, 0, stream>>>(
        bufBh, W2, dinv, nullptr, bufDh, n);

    // agg2: bufEh = fp16(relu(dinv*agg(bufDh)+b2)), zero-padded to 64h rows
    agg2_h16<<<(n + 31) / 32, 256, 0, stream>>>(bufDh, offs, csr, dinv, b2, bufEh, n);

    // gemm3: bufCh = fp16((bufEh@W3)*dinv) s32h  [K=52 (rows 50..51 zero), KR=50]
    gemm_tiled_h<52, 25, 144, 64, 32, true, false, 50><<<(n + 143) / 144, 256, 0, stream>>>(
        bufEh, W3, dinv, nullptr, bufCh, n);

    // agg3 + MLP head -> d_out
    agg3_mlp_h<<<(n + 63) / 64, 256, 0, stream>>>(
        bufCh, offs, csr, dinv, b3, Wl1, bl1, Wl2, bl2, Wl3, bl3, (float*)d_out, n);
}

// Round 15
// 283.303 us; speedup vs baseline: 1.0822x; 1.0822x over previous
//
#include <hip/hip_runtime.h>
#include <hip/hip_fp16.h>
#include <cstdint>

constexpr int BSHIFT = 9;               // 512 nodes per bucket
constexpr int NBUCK  = 256;             // max buckets (covers 131072 nodes)
constexpr int BUCKET_CAP = 6144;        // slot capacity; E/bucket ~ Poisson(5102), 14 sigma

struct alignas(16) H8 { __half2 a, b, c, d; };
struct alignas(8)  H4 { __half2 a, b; };

__device__ __forceinline__ float4 add4(float4 a, float4 b) {
    return make_float4(a.x + b.x, a.y + b.y, a.z + b.z, a.w + b.w);
}
__device__ __forceinline__ float4 mul4s(float4 a, float s) {
    return make_float4(a.x * s, a.y * s, a.z * s, a.w * s);
}
__device__ __forceinline__ void acc_h8(float4& A0, float4& A1, const H8 v, float s) {
    float2 f0 = __half22float2(v.a), f1 = __half22float2(v.b);
    float2 f2 = __half22float2(v.c), f3 = __half22float2(v.d);
    A0.x = fmaf(f0.x, s, A0.x); A0.y = fmaf(f0.y, s, A0.y);
    A0.z = fmaf(f1.x, s, A0.z); A0.w = fmaf(f1.y, s, A0.w);
    A1.x = fmaf(f2.x, s, A1.x); A1.y = fmaf(f2.y, s, A1.y);
    A1.z = fmaf(f3.x, s, A1.z); A1.w = fmaf(f3.y, s, A1.w);
}

// ---------------- CSR build (R12-proven: LDS-local bucket_csr) ----------------

constexpr int EPT = 16;  // edges per thread; chunk = 4096
__global__ __launch_bounds__(256) void partition_edges(
    const int* __restrict__ src, const int* __restrict__ dst,
    int* __restrict__ bucketCur, int* __restrict__ pairs, int ne) {
    __shared__ int lcnt[NBUCK];
    __shared__ int lbase[NBUCK];
    int base = blockIdx.x * (256 * EPT);
    if (threadIdx.x < NBUCK) lcnt[threadIdx.x] = 0;
    __syncthreads();
    int2 ed[EPT];
    int  rnk[EPT];
#pragma unroll
    for (int j = 0; j < EPT; ++j) {
        int e = base + j * 256 + threadIdx.x;
        if (e < ne) {
            int d = dst[e];
            ed[j] = make_int2(src[e], d);
            rnk[j] = atomicAdd(&lcnt[d >> BSHIFT], 1);
        } else {
            ed[j].y = -1;
        }
    }
    __syncthreads();
    if (threadIdx.x < NBUCK) {
        int c = lcnt[threadIdx.x];
        lbase[threadIdx.x] = c ? atomicAdd(&bucketCur[threadIdx.x], c) : 0;
    }
    __syncthreads();
#pragma unroll
    for (int j = 0; j < EPT; ++j) {
        if (ed[j].y >= 0) {
            int b = ed[j].y >> BSHIFT;
            int p = lbase[b] + rnk[j];
            if (p < BUCKET_CAP)
                pairs[(size_t)b * BUCKET_CAP + p] =
                    (ed[j].x << BSHIFT) | (ed[j].y & ((1 << BSHIFT) - 1));
        }
    }
}

__global__ void scan_buckets(const int* __restrict__ bucketCnt, int* __restrict__ bucketBase,
                             int* __restrict__ offs, int n, int ne, int nbuckets) {
    __shared__ int tmp[256];
    int c = (threadIdx.x < (unsigned)nbuckets) ? bucketCnt[threadIdx.x] : 0;
    tmp[threadIdx.x] = c;
    __syncthreads();
    for (int off = 1; off < 256; off <<= 1) {
        int t = (threadIdx.x >= (unsigned)off) ? tmp[threadIdx.x - off] : 0;
        __syncthreads();
        tmp[threadIdx.x] += t;
        __syncthreads();
    }
    if (threadIdx.x < (unsigned)nbuckets) bucketBase[threadIdx.x] = tmp[threadIdx.x] - c;
    if (threadIdx.x == 0) offs[n] = ne;
}

__global__ __launch_bounds__(256) void bucket_csr(
    const int* __restrict__ pairs, const int* __restrict__ bucketCnt,
    const int* __restrict__ bucketBase, int* __restrict__ offs,
    float* __restrict__ dinv, int* __restrict__ csr, int n) {
    constexpr int BN = 1 << BSHIFT;  // 512
    __shared__ int hist[BN];
    __shared__ int cur[BN];
    __shared__ int tmp[256];
    int b = blockIdx.x;
    int cnt  = bucketCnt[b];
    int base = bucketBase[b];
    const int* pb = pairs + (size_t)b * BUCKET_CAP;
    int nodeLo = b << BSHIFT;

    hist[threadIdx.x] = 0;
    hist[threadIdx.x + 256] = 0;
    __syncthreads();
    for (int e = threadIdx.x; e < cnt; e += 256)
        atomicAdd(&hist[pb[e] & (BN - 1)], 1);
    __syncthreads();

    int l0 = 2 * threadIdx.x, l1 = l0 + 1;
    int h0 = hist[l0], h1 = hist[l1];
    tmp[threadIdx.x] = h0 + h1;
    __syncthreads();
    for (int off = 1; off < 256; off <<= 1) {
        int t = (threadIdx.x >= (unsigned)off) ? tmp[threadIdx.x - off] : 0;
        __syncthreads();
        tmp[threadIdx.x] += t;
        __syncthreads();
    }
    int e0 = tmp[threadIdx.x] - (h0 + h1);
    int e1 = e0 + h0;
    int g0 = nodeLo + l0, g1 = nodeLo + l1;
    if (g0 < n) { offs[g0] = base + e0; dinv[g0] = rsqrtf((float)(h0 + 1)); }
    if (g1 < n) { offs[g1] = base + e1; dinv[g1] = rsqrtf((float)(h1 + 1)); }
    cur[l0] = e0;
    cur[l1] = e1;
    __syncthreads();

    for (int e = threadIdx.x; e < cnt; e += 256) {
        int p = pb[e];
        int pos = atomicAdd(&cur[p & (BN - 1)], 1);
        csr[base + pos] = ((unsigned)p) >> BSHIFT;
    }
}

// ---------------- fp32 -> fp16 streaming convert ----------------
__global__ void cvt_f32_f16(const float* __restrict__ x, __half* __restrict__ o, int n4) {
    int i = blockIdx.x * blockDim.x + threadIdx.x;
    if (i < n4) {
        float4 v = ((const float4*)x)[i];
        H4 h;
        h.a = __floats2half2_rn(v.x, v.y);
        h.b = __floats2half2_rn(v.z, v.w);
        ((H4*)o)[i] = h;
    }
}

// ---------------- agg1: fp16 gather (K=64), fp32 accumulate, fp16 out ----------------
__global__ __launch_bounds__(256) void agg1_h(
    const __half* __restrict__ s, const int* __restrict__ offs,
    const int* __restrict__ csr, const float* __restrict__ dinv,
    __half* __restrict__ out, int n) {
    int lane = threadIdx.x & 7;
    int node = blockIdx.x * 32 + (threadIdx.x >> 3);
    if (node >= n) return;
    int f0 = lane * 8;
    float dv = dinv[node];

    float4 z = make_float4(0.f, 0.f, 0.f, 0.f);
    float4 a00 = z, a01 = z, a10 = z, a11 = z, a20 = z, a21 = z, a30 = z, a31 = z;
    {
        H8 sv = *(const H8*)&s[(size_t)node * 64 + f0];
        acc_h8(a00, a01, sv, dv);
    }
    int e0 = offs[node], e1 = offs[node + 1];
    int e = e0;
    for (; e + 4 <= e1; e += 4) {
        int i0 = csr[e], i1 = csr[e + 1], i2 = csr[e + 2], i3 = csr[e + 3];
        H8 v0 = *(const H8*)&s[(size_t)i0 * 64 + f0];
        H8 v1 = *(const H8*)&s[(size_t)i1 * 64 + f0];
        H8 v2 = *(const H8*)&s[(size_t)i2 * 64 + f0];
        H8 v3 = *(const H8*)&s[(size_t)i3 * 64 + f0];
        acc_h8(a00, a01, v0, dinv[i0]);
        acc_h8(a10, a11, v1, dinv[i1]);
        acc_h8(a20, a21, v2, dinv[i2]);
        acc_h8(a30, a31, v3, dinv[i3]);
    }
    for (; e < e1; ++e) {
        int sid = csr[e];
        H8 v = *(const H8*)&s[(size_t)sid * 64 + f0];
        acc_h8(a00, a01, v, dinv[sid]);
    }
    float4 A0 = add4(add4(a00, a10), add4(a20, a30));
    float4 A1 = add4(add4(a01, a11), add4(a21, a31));
    A0 = mul4s(A0, dv);
    A1 = mul4s(A1, dv);

    H8 h;
    h.a = __floats2half2_rn(A0.x, A0.y);
    h.b = __floats2half2_rn(A0.z, A0.w);
    h.c = __floats2half2_rn(A1.x, A1.y);
    h.d = __floats2half2_rn(A1.z, A1.w);
    *(H8*)&out[(size_t)node * 64 + f0] = h;
}

// ---------------- agg2: fp16 gather (M=50 in s64h rows), fp16 out (zero-padded) ---------
__global__ __launch_bounds__(256) void agg2_h16(
    const __half* __restrict__ s, const int* __restrict__ offs,
    const int* __restrict__ csr, const float* __restrict__ dinv,
    const float* __restrict__ b, __half* __restrict__ out, int n) {
    constexpr int MH = 50, SH = 64;
    int lane = threadIdx.x & 7;
    int node = blockIdx.x * 32 + (threadIdx.x >> 3);
    if (node >= n) return;
    int f0 = lane * 8;
    H8 zh{};
    if (f0 >= 56) {              // lane 7: pure zero-pad (halves 56..63)
        *(H8*)&out[(size_t)node * SH + f0] = zh;
        return;
    }
    float dv = dinv[node];

    float4 z = make_float4(0.f, 0.f, 0.f, 0.f);
    float4 a00 = z, a01 = z, a10 = z, a11 = z, a20 = z, a21 = z, a30 = z, a31 = z;
    {
        H8 sv = *(const H8*)&s[(size_t)node * SH + f0];
        acc_h8(a00, a01, sv, 1.0f);
    }
    int e0 = offs[node], e1 = offs[node + 1];
    int e = e0;
    for (; e + 4 <= e1; e += 4) {
        int i0 = csr[e], i1 = csr[e + 1], i2 = csr[e + 2], i3 = csr[e + 3];
        H8 v0 = *(const H8*)&s[(size_t)i0 * SH + f0];
        H8 v1 = *(const H8*)&s[(size_t)i1 * SH + f0];
        H8 v2 = *(const H8*)&s[(size_t)i2 * SH + f0];
        H8 v3 = *(const H8*)&s[(size_t)i3 * SH + f0];
        acc_h8(a00, a01, v0, 1.0f);
        acc_h8(a10, a11, v1, 1.0f);
        acc_h8(a20, a21, v2, 1.0f);
        acc_h8(a30, a31, v3, 1.0f);
    }
    for (; e < e1; ++e) {
        H8 v = *(const H8*)&s[(size_t)csr[e] * SH + f0];
        acc_h8(a00, a01, v, 1.0f);
    }
    float4 A0 = add4(add4(a00, a10), add4(a20, a30));
    float4 A1 = add4(add4(a01, a11), add4(a21, a31));
    float v[8] = {A0.x, A0.y, A0.z, A0.w, A1.x, A1.y, A1.z, A1.w};
#pragma unroll
    for (int i = 0; i < 8; ++i)
        v[i] = (f0 + i < MH) ? fmaxf(dv * v[i] + b[f0 + i], 0.0f) : 0.0f;
    H8 h;
    h.a = __floats2half2_rn(v[0], v[1]);
    h.b = __floats2half2_rn(v[2], v[3]);
    h.c = __floats2half2_rn(v[4], v[5]);
    h.d = __floats2half2_rn(v[6], v[7]);
    *(H8*)&out[(size_t)node * SH + f0] = h;
}

// ---------------- register-tiled GEMM: fp16 in/out, W in LDS ----------------
// KR = real K rows in W (rows >= KR staged as zero; Xs rows >= KR may be junk*0).
template <int K, int M, int NT, int XS, int OS, bool SCALE, bool BIAS_RELU, int KR>
__global__ __launch_bounds__(256) void gemm_tiled_h(
    const __half* __restrict__ x, const float* __restrict__ W,
    const float* __restrict__ dinv, const float* __restrict__ b,
    __half* __restrict__ out, int n) {
    static_assert(NT % 4 == 0 && K % 4 == 0 && OS % 4 == 0, "");
    constexpr int Mp  = (M + 3) & ~3;
    constexpr int MQ  = Mp / 4;
    constexpr int NTp = NT + 4;
    constexpr int NTILES = (NT / 4) * MQ;
    static_assert(NTILES <= 256, "");
    static_assert(M % 4 != 0 || KR == K, "float4 W path assumes KR==K");

    __shared__ float Xs[K * NTp];
    __shared__ float Ws[K * Mp];

    if constexpr (M % 4 == 0) {
        for (int i = threadIdx.x; i < K * M / 4; i += 256)
            ((float4*)Ws)[i] = ((const float4*)W)[i];
    } else if constexpr (M % 2 == 0) {
        constexpr int C2 = Mp / 2;
        for (int i = threadIdx.x; i < K * C2; i += 256) {
            int r = i / C2, c = i - r * C2;
            float2 v = make_float2(0.0f, 0.0f);
            if (r < KR) {
                if (c * 2 + 1 < M)  v = *(const float2*)&W[r * M + c * 2];
                else if (c * 2 < M) v = make_float2(W[r * M + c * 2], 0.0f);
            }
            *(float2*)&Ws[r * Mp + c * 2] = v;
        }
    } else {
        for (int i = threadIdx.x; i < K * Mp; i += 256) {
            int r = i / Mp, c = i - r * Mp;
            Ws[i] = (c < M && r < KR) ? W[r * M + c] : 0.0f;
        }
    }

    int nodeBase = blockIdx.x * NT;
    constexpr int KVH = (K % 8 == 0) ? 8 : 4;
    for (int it = threadIdx.x; it < NT * (K / KVH); it += 256) {
        int node = it % NT;
        int kv = it / NT;
        int gn = nodeBase + node;
        if constexpr (KVH == 8) {
            H8 h{};
            if (gn < n) h = *(const H8*)&x[(size_t)gn * XS + kv * 8];
            float2 f0_ = __half22float2(h.a), f1_ = __half22float2(h.b);
            float2 f2_ = __half22float2(h.c), f3_ = __half22float2(h.d);
            Xs[(kv * 8 + 0) * NTp + node] = f0_.x;
            Xs[(kv * 8 + 1) * NTp + node] = f0_.y;
            Xs[(kv * 8 + 2) * NTp + node] = f1_.x;
            Xs[(kv * 8 + 3) * NTp + node] = f1_.y;
            Xs[(kv * 8 + 4) * NTp + node] = f2_.x;
            Xs[(kv * 8 + 5) * NTp + node] = f2_.y;
            Xs[(kv * 8 + 6) * NTp + node] = f3_.x;
            Xs[(kv * 8 + 7) * NTp + node] = f3_.y;
        } else {
            H4 h{};
            if (gn < n) h = *(const H4*)&x[(size_t)gn * XS + kv * 4];
            float2 f0_ = __half22float2(h.a), f1_ = __half22float2(h.b);
            Xs[(kv * 4 + 0) * NTp + node] = f0_.x;
            Xs[(kv * 4 + 1) * NTp + node] = f0_.y;
            Xs[(kv * 4 + 2) * NTp + node] = f1_.x;
            Xs[(kv * 4 + 3) * NTp + node] = f1_.y;
        }
    }
    __syncthreads();

    int t = threadIdx.x;
    if (t >= NTILES) return;
    int ng = t / MQ, mq = t - ng * MQ;
    int n0 = ng * 4;
    int m0 = mq * 4;

    float acc[4][4];
#pragma unroll
    for (int j = 0; j < 4; ++j)
#pragma unroll
        for (int i = 0; i < 4; ++i) acc[j][i] = 0.0f;

#pragma unroll 4
    for (int k = 0; k < K; ++k) {
        float4 xv = *(const float4*)&Xs[k * NTp + n0];
        float4 wv = *(const float4*)&Ws[k * Mp + m0];
        acc[0][0] = fmaf(xv.x, wv.x, acc[0][0]); acc[0][1] = fmaf(xv.x, wv.y, acc[0][1]);
        acc[0][2] = fmaf(xv.x, wv.z, acc[0][2]); acc[0][3] = fmaf(xv.x, wv.w, acc[0][3]);
        acc[1][0] = fmaf(xv.y, wv.x, acc[1][0]); acc[1][1] = fmaf(xv.y, wv.y, acc[1][1]);
        acc[1][2] = fmaf(xv.y, wv.z, acc[1][2]); acc[1][3] = fmaf(xv.y, wv.w, acc[1][3]);
        acc[2][0] = fmaf(xv.z, wv.x, acc[2][0]); acc[2][1] = fmaf(xv.z, wv.y, acc[2][1]);
        acc[2][2] = fmaf(xv.z, wv.z, acc[2][2]); acc[2][3] = fmaf(xv.z, wv.w, acc[2][3]);
        acc[3][0] = fmaf(xv.w, wv.x, acc[3][0]); acc[3][1] = fmaf(xv.w, wv.y, acc[3][1]);
        acc[3][2] = fmaf(xv.w, wv.z, acc[3][2]); acc[3][3] = fmaf(xv.w, wv.w, acc[3][3]);
    }

#pragma unroll
    for (int j = 0; j < 4; ++j) {
        int nd = nodeBase + n0 + j;
        if (nd >= n) continue;
        float dv = SCALE ? dinv[nd] : 1.0f;
        float r[4];
#pragma unroll
        for (int i = 0; i < 4; ++i) {
            r[i] = acc[j][i];
            if (SCALE) r[i] *= dv;
            if (BIAS_RELU) r[i] = fmaxf(r[i] + b[m0 + i], 0.0f);
        }
        if (m0 + 3 < M) {
            H4 h;
            h.a = __floats2half2_rn(r[0], r[1]);
            h.b = __floats2half2_rn(r[2], r[3]);
            *(H4*)&out[(size_t)nd * OS + m0] = h;
        } else {
#pragma unroll
            for (int i = 0; i < 4; ++i)
                if (m0 + i < M) out[(size_t)nd * OS + m0 + i] = __float2half_rn(r[i]);
        }
    }
}

// ---------------- agg3 (fp16 gather, 1 line/row) + MLP head ----------------
__global__ __launch_bounds__(256) void agg3_mlp_h(
    const __half* __restrict__ s, const int* __restrict__ offs,
    const int* __restrict__ csr, const float* __restrict__ dinv,
    const float* __restrict__ bg,
    const float* __restrict__ Wl1, const float* __restrict__ bl1,
    const float* __restrict__ Wl2, const float* __restrict__ bl2,
    const float* __restrict__ Wl3, const float* __restrict__ bl3,
    float* __restrict__ out, int n) {
    constexpr int MH = 25, SH = 32, LPN = 4;
    __shared__ float W1s[625], W2s[250], W3s[10], b1s[25], b2s[10];
    __shared__ float accs[64 * 26];
    __shared__ float b3s;

    for (int i = threadIdx.x; i < 625; i += 256) W1s[i] = Wl1[i];
    for (int i = threadIdx.x; i < 250; i += 256) W2s[i] = Wl2[i];
    if (threadIdx.x < 10) { W3s[threadIdx.x] = Wl3[threadIdx.x]; b2s[threadIdx.x] = bl2[threadIdx.x]; }
    if (threadIdx.x < 25) b1s[threadIdx.x] = bl1[threadIdx.x];
    if (threadIdx.x == 0) b3s = bl3[0];

    int lane = threadIdx.x % LPN;
    int nl   = threadIdx.x / LPN;
    int node = blockIdx.x * 64 + nl;
    int f0 = lane * 8;

    if (node < n && f0 < MH) {
        float dv = dinv[node];
        float4 z = make_float4(0.f, 0.f, 0.f, 0.f);
        float4 a00 = z, a01 = z, a10 = z, a11 = z, a20 = z, a21 = z, a30 = z, a31 = z;
        {
            H8 sv = *(const H8*)&s[(size_t)node * SH + f0];
            acc_h8(a00, a01, sv, 1.0f);
        }
        int e0 = offs[node], e1 = offs[node + 1];
        int e = e0;
        for (; e + 4 <= e1; e += 4) {
            int i0 = csr[e], i1 = csr[e + 1], i2 = csr[e + 2], i3 = csr[e + 3];
            H8 v0 = *(const H8*)&s[(size_t)i0 * SH + f0];
            H8 v1 = *(const H8*)&s[(size_t)i1 * SH + f0];
            H8 v2 = *(const H8*)&s[(size_t)i2 * SH + f0];
            H8 v3 = *(const H8*)&s[(size_t)i3 * SH + f0];
            acc_h8(a00, a01, v0, 1.0f);
            acc_h8(a10, a11, v1, 1.0f);
            acc_h8(a20, a21, v2, 1.0f);
            acc_h8(a30, a31, v3, 1.0f);
        }
        for (; e < e1; ++e) {
            H8 v = *(const H8*)&s[(size_t)csr[e] * SH + f0];
            acc_h8(a00, a01, v, 1.0f);
        }
        float4 A0 = add4(add4(a00, a10), add4(a20, a30));
        float4 A1 = add4(add4(a01, a11), add4(a21, a31));
        float v[8] = {A0.x, A0.y, A0.z, A0.w, A1.x, A1.y, A1.z, A1.w};
#pragma unroll
        for (int i = 0; i < 8; ++i)
            if (f0 + i < MH)
                accs[nl * 26 + f0 + i] = fmaxf(dv * v[i] + bg[f0 + i], 0.0f);
    }
    __syncthreads();

    if (threadIdx.x < 64) {
        int nd = blockIdx.x * 64 + threadIdx.x;
        if (nd < n) {
            const float* xr = &accs[threadIdx.x * 26];
            float h1[25];
#pragma unroll
            for (int m = 0; m < 25; ++m) {
                float a = b1s[m];
#pragma unroll
                for (int k = 0; k < 25; ++k) a = fmaf(xr[k], W1s[k * 25 + m], a);
                h1[m] = fmaxf(a, 0.0f);
            }
            float h2[10];
#pragma unroll
            for (int m = 0; m < 10; ++m) {
                float a = b2s[m];
#pragma unroll
                for (int k = 0; k < 25; ++k) a = fmaf(h1[k], W2s[k * 10 + m], a);
                h2[m] = fmaxf(a, 0.0f);
            }
            float a = b3s;
#pragma unroll
            for (int k = 0; k < 10; ++k) a = fmaf(h2[k], W3s[k], a);
            out[nd] = fmaxf(a, 0.0f);
        }
    }
}

// ---------------- launch ----------------

extern "C" void kernel_launch(void* const* d_in, const int* in_sizes, int n_in,
                              void* d_out, int out_size, void* d_ws, size_t ws_size,
                              hipStream_t stream) {
    const float* x0  = (const float*)d_in[0];
    const float* W1  = (const float*)d_in[1];
    const float* b1  = (const float*)d_in[2];
    const float* W2  = (const float*)d_in[3];
    const float* b2  = (const float*)d_in[4];
    const float* W3  = (const float*)d_in[5];
    const float* b3  = (const float*)d_in[6];
    const float* Wl1 = (const float*)d_in[7];
    const float* bl1 = (const float*)d_in[8];
    const float* Wl2 = (const float*)d_in[9];
    const float* bl2 = (const float*)d_in[10];
    const float* Wl3 = (const float*)d_in[11];
    const float* bl3 = (const float*)d_in[12];
    const int*   edge = (const int*)d_in[13];

    int n  = in_sizes[0] / 64;      // 100000
    int ne = in_sizes[13] / 2;      // 1000000
    const int* esrc = edge;
    const int* edst = edge + ne;

    char* ws = (char*)d_ws;
    auto alloc = [&](size_t bytes) {
        char* p = ws;
        ws += (bytes + 255) & ~(size_t)255;
        return p;
    };
    int*    offs       = (int*)alloc((size_t)(n + 1) * 4);
    int*    bucketCur  = (int*)alloc(NBUCK * 4);
    int*    bucketBase = (int*)alloc(NBUCK * 4);
    int*    csr        = (int*)alloc((size_t)ne * 4);
    float*  dinv       = (float*)alloc((size_t)n * 4);
    __half* x0h        = (__half*)alloc((size_t)n * 64 * 2);   // fp16 s64h (cvt out)
    __half* bufAh      = (__half*)alloc((size_t)n * 64 * 2);   // fp16 s64h (agg1 out)
    __half* bufBh      = (__half*)alloc((size_t)n * 112 * 2);  // fp16 s112h (gemm1 out)
    __half* bufDh      = (__half*)alloc((size_t)n * 64 * 2);   // fp16 s64h (gemm2 out)
    // aliases (ordered lifetimes):
    //   pairs (6.3MB) in bufBh: consumed by bucket_csr before gemm1 writes bufBh
    //   bufEh (agg2 out, s64h) aliases x0h (dead after agg1)
    //   bufCh (gemm3 out, s32h) aliases bufAh (dead after gemm1)
    int*    pairs = (int*)bufBh;
    __half* bufEh = x0h;
    __half* bufCh = bufAh;
    (void)ws_size; (void)n_in; (void)out_size;

    int nbuckets = (n + (1 << BSHIFT) - 1) >> BSHIFT;   // 196

    // CSR + dinv (memset + 3 dispatches; R12-proven LDS-local scatter)
    hipMemsetAsync(bucketCur, 0, NBUCK * 4, stream);
    partition_edges<<<(ne + 256 * EPT - 1) / (256 * EPT), 256, 0, stream>>>(
        esrc, edst, bucketCur, pairs, ne);
    scan_buckets<<<1, 256, 0, stream>>>(bucketCur, bucketBase, offs, n, ne, nbuckets);
    bucket_csr<<<nbuckets, 256, 0, stream>>>(pairs, bucketCur, bucketBase, offs, dinv, csr, n);

    // x0h = fp16(x0)
    cvt_f32_f16<<<(n * 16 + 255) / 256, 256, 0, stream>>>(x0, x0h, n * 16);

    // agg1: bufAh = fp16(ÂX)
    agg1_h<<<(n + 31) / 32, 256, 0, stream>>>(x0h, offs, csr, dinv, bufAh, n);

    // gemm1: bufBh = fp16(relu(bufAh@W1 + b1))   [K=64 -> M=100]
    gemm_tiled_h<64, 100, 40, 64, 112, false, true, 64><<<(n + 39) / 40, 256, 0, stream>>>(
        bufAh, W1, nullptr, b1, bufBh, n);

    // gemm2: bufDh = fp16((bufBh@W2)*dinv)       [K=100 -> M=50]
    gemm_tiled_h<100, 50, 64, 112, 64, true, false, 100><<<(n + 63) / 64, 256, 0, stream>>>(
        bufBh, W2, dinv, nullptr, bufDh, n);

    // agg2: bufEh = fp16(relu(dinv*agg(bufDh)+b2)), zero-padded to 64h rows
    agg2_h16<<<(n + 31) / 32, 256, 0, stream>>>(bufDh, offs, csr, dinv, b2, bufEh, n);

    // gemm3: bufCh = fp16((bufEh@W3)*dinv) s32h  [K=52 (rows 50..51 zero), KR=50]
    gemm_tiled_h<52, 25, 144, 64, 32, true, false, 50><<<(n + 143) / 144, 256, 0, stream>>>(
        bufEh, W3, dinv, nullptr, bufCh, n);

    // agg3 + MLP head -> d_out
    agg3_mlp_h<<<(n + 63) / 64, 256, 0, stream>>>(
        bufCh, offs, csr, dinv, b3, Wl1, bl1, Wl2, bl2, Wl3, bl3, (float*)d_out, n);
}